// Round 3
// baseline (319.417 us; speedup 1.0000x reference)
//
#include <hip/hip_runtime.h>
#include <hip/hip_cooperative_groups.h>

namespace cg = cooperative_groups;

// Problem constants (fixed by the reference)
#define NNZ_  524288
#define S_    8192
#define OUT_  8192
#define CAP   192     // per-column bucket capacity; counts ~ Poisson(64), 192 is ~12 sigma
#define GRID  1024    // 4 blocks/CU on 256 CUs -> co-residency guaranteed
#define BLK   256

// One fused cooperative kernel:
//   phase 0: zero per-column counters
//   phase 1: bucket triples by column; entry packs (row<<19)|orig_idx in 4B
//   phase 2: one wave per column: dedupe (numpy last-write-wins = max orig idx
//            per (row,col)), gather-accumulate, wave-reduce, +bias
__global__ void __launch_bounds__(BLK, 4) fused_kernel(
    const float* __restrict__ x, const float* __restrict__ W,
    const float* __restrict__ b, const int* __restrict__ rows,
    const int* __restrict__ cols, const int* __restrict__ wpos,
    const int* __restrict__ bias_pos,
    int* __restrict__ cnt, unsigned* __restrict__ buckets,
    float* __restrict__ out)
{
    cg::grid_group grid = cg::this_grid();
    const int tid   = blockIdx.x * BLK + threadIdx.x;
    const int total = GRID * BLK;

    // ---- Phase 0: zero counters (ws is poisoned 0xAA before every launch)
    for (int c = tid; c < OUT_; c += total) cnt[c] = 0;
    grid.sync();

    // ---- Phase 1: scatter. Coalesced reads of cols/rows; random 4B bucket
    // store. Packed entry: high 13 bits = row, low 19 bits = original index.
    for (int i = tid; i < NNZ_; i += total) {
        int c = cols[i];
        unsigned e = ((unsigned)rows[i] << 19) | (unsigned)i;
        int p = atomicAdd(&cnt[c], 1);
        if (p < CAP) buckets[c * CAP + p] = e;
    }
    grid.sync();

    // ---- Phase 2: one 64-lane wave per column, barrier-free (wave-private
    // LDS slice; intra-wave DS ops are in-order so no __syncthreads needed).
    __shared__ unsigned sb[BLK / 64][CAP];
    const int wave = threadIdx.x >> 6;
    const int lane = threadIdx.x & 63;
    const int gw   = tid >> 6;        // global wave id
    const int nw   = total >> 6;      // total waves (4096 -> 2 columns each)

    unsigned* s = sb[wave];
    for (int c = gw; c < OUT_; c += nw) {
        int k = cnt[c]; if (k > CAP) k = CAP;
        for (int m = lane; m < k; m += 64) s[m] = buckets[c * CAP + m];
        float acc = 0.f;
        for (int m = lane; m < k; m += 64) {
            unsigned mine = s[m];
            // last-write-wins: lose iff same row (high 13 bits) and larger
            // original index (low 19 bits). Packed compare does both.
            bool win = true;
            for (int t = 0; t < k; ++t) {
                unsigned o = s[t];   // same addr across lanes -> LDS broadcast
                if (((mine ^ o) >> 19) == 0u && o > mine) { win = false; break; }
            }
            if (win) {
                int i = (int)(mine & 0x7FFFFu);
                int r = (int)(mine >> 19);
                acc += x[r] * W[wpos[i]];   // x: 32KB (L1), W: 120KB (L2)
            }
        }
        for (int off = 32; off; off >>= 1) acc += __shfl_down(acc, off, 64);
        if (lane == 0) out[c] = acc + b[bias_pos[c]];
    }
}

extern "C" void kernel_launch(void* const* d_in, const int* in_sizes, int n_in,
                              void* d_out, int out_size, void* d_ws, size_t ws_size,
                              hipStream_t stream) {
    const float* x    = (const float*)d_in[0];
    const float* Pw   = (const float*)d_in[1];
    const float* Pb   = (const float*)d_in[2];
    const int*   rows = (const int*)d_in[3];
    const int*   cols = (const int*)d_in[4];
    const int*   wpos = (const int*)d_in[5];
    const int*   bpos = (const int*)d_in[6];
    float*       out  = (float*)d_out;

    // Workspace layout: cnt[OUT_] | buckets[OUT_][CAP]   (~6.03 MB, proven fit)
    int*      cnt     = (int*)d_ws;
    unsigned* buckets = (unsigned*)(cnt + OUT_);

    void* args[] = { (void*)&x, (void*)&Pw, (void*)&Pb, (void*)&rows,
                     (void*)&cols, (void*)&wpos, (void*)&bpos,
                     (void*)&cnt, (void*)&buckets, (void*)&out };
    hipLaunchCooperativeKernel((const void*)fused_kernel, dim3(GRID), dim3(BLK),
                               args, 0, stream);
}

// Round 4
// 124.063 us; speedup vs baseline: 2.5746x; 2.5746x over previous
//
#include <hip/hip_runtime.h>

// Problem constants (fixed by the reference)
#define NNZ_  524288
#define S_    8192
#define OUT_  8192
#define CAP   192     // per-column capacity; counts ~ Poisson(64), 192 ~ 12 sigma (data fixed by seed)

// Pass 1: bucket triples by column. Entry packs (row:13 | orig_idx:19) in 4B
// so pass 2 never touches rows[]. int4-vectorized: 4 independent
// atomic->store chains per thread for ILP; 131072 threads total.
__global__ void __launch_bounds__(256) scatter_kernel(
    const int* __restrict__ rows, const int* __restrict__ cols,
    int* __restrict__ cnt, unsigned* __restrict__ buckets)
{
    const int t = blockIdx.x * 256 + threadIdx.x;       // grid = NNZ_/4/256 = 512
    const int4 c = ((const int4*)cols)[t];
    const int4 r = ((const int4*)rows)[t];
    const int base = t * 4;
    const int p0 = atomicAdd(&cnt[c.x], 1);
    const int p1 = atomicAdd(&cnt[c.y], 1);
    const int p2 = atomicAdd(&cnt[c.z], 1);
    const int p3 = atomicAdd(&cnt[c.w], 1);
    if (p0 < CAP) buckets[c.x * CAP + p0] = ((unsigned)r.x << 19) | (unsigned)(base + 0);
    if (p1 < CAP) buckets[c.y * CAP + p1] = ((unsigned)r.y << 19) | (unsigned)(base + 1);
    if (p2 < CAP) buckets[c.z * CAP + p2] = ((unsigned)r.z << 19) | (unsigned)(base + 2);
    if (p3 < CAP) buckets[c.w * CAP + p3] = ((unsigned)r.w << 19) | (unsigned)(base + 3);
}

// Pass 2: one 64-lane wave per column, wave-private LDS slice (no block
// barrier needed — intra-wave DS ordering suffices; proven in round 3).
// Winner rule (numpy last-write-wins): entry loses iff another entry in the
// column has the same row (high 13 bits) and larger orig idx (low 19 bits);
// the packed compare does both at once.
__global__ void __launch_bounds__(256) col_kernel(
    const float* __restrict__ x, const float* __restrict__ W,
    const float* __restrict__ b, const int* __restrict__ wpos,
    const int* __restrict__ bias_pos, const int* __restrict__ cnt,
    const unsigned* __restrict__ buckets, float* __restrict__ out)
{
    __shared__ unsigned sb[4][CAP];
    const int wave = threadIdx.x >> 6;
    const int lane = threadIdx.x & 63;
    const int c = blockIdx.x * 4 + wave;   // grid = OUT_/4 = 2048 blocks

    int k = cnt[c]; if (k > CAP) k = CAP;
    unsigned* s = sb[wave];
    for (int m = lane; m < k; m += 64) s[m] = buckets[c * CAP + m];

    float acc = 0.f;
    for (int m = lane; m < k; m += 64) {
        const unsigned mine = s[m];
        bool win = true;
        for (int tt = 0; tt < k; ++tt) {
            const unsigned o = s[tt];        // same addr across lanes -> LDS broadcast
            if (((mine ^ o) >> 19) == 0u && o > mine) { win = false; break; }
        }
        if (win) acc += x[mine >> 19] * W[wpos[mine & 0x7FFFFu]];  // x,W: L1/L2-resident
    }
    for (int off = 32; off; off >>= 1) acc += __shfl_down(acc, off, 64);
    if (lane == 0) out[c] = acc + b[bias_pos[c]];
}

extern "C" void kernel_launch(void* const* d_in, const int* in_sizes, int n_in,
                              void* d_out, int out_size, void* d_ws, size_t ws_size,
                              hipStream_t stream) {
    const float* x    = (const float*)d_in[0];
    const float* Pw   = (const float*)d_in[1];
    const float* Pb   = (const float*)d_in[2];
    const int*   rows = (const int*)d_in[3];
    const int*   cols = (const int*)d_in[4];
    const int*   wpos = (const int*)d_in[5];
    const int*   bpos = (const int*)d_in[6];
    float*       out  = (float*)d_out;

    // Workspace: cnt[OUT_] | buckets[OUT_][CAP]  (~6.03 MB, proven fit)
    int*      cnt     = (int*)d_ws;
    unsigned* buckets = (unsigned*)(cnt + OUT_);

    hipMemsetAsync(cnt, 0, OUT_ * sizeof(int), stream);
    scatter_kernel<<<NNZ_ / 4 / 256, 256, 0, stream>>>(rows, cols, cnt, buckets);
    col_kernel<<<OUT_ / 4, 256, 0, stream>>>(x, Pw, Pb, wpos, bpos, cnt, buckets, out);
}